// Round 1
// baseline (1219.206 us; speedup 1.0000x reference)
//
#include <hip/hip_runtime.h>
#include <hip/hip_bf16.h>

// GAT layer: N=100000 nodes, E=3200000 edges, IN_DIM=128, OUT_DIM=64.
// Inputs: x(N,128) f32, edge_index(2,E) i32, edge_weight(E) f32,
//         W(128,64) f32, a_src(64) f32, a_tgt(64) f32.
// Output: (N,64) f32.

#define IN_DIM 128
#define OUT_DIM 64

// ---------------- Kernel 1: h = x@W, hs = h.a_src, ht = h.a_tgt -------------
// One wave (64 lanes) per node; lane d computes h[node][d].
__global__ __launch_bounds__(256) void k_linear(
    const float* __restrict__ x, const float* __restrict__ W,
    const float* __restrict__ a_src, const float* __restrict__ a_tgt,
    float* __restrict__ h, float* __restrict__ hs, float* __restrict__ ht,
    int n)
{
    __shared__ float xs[4][IN_DIM];
    const int lane = threadIdx.x & 63;
    const int wv   = threadIdx.x >> 6;
    const int node = blockIdx.x * 4 + wv;
    const bool valid = node < n;

    if (valid) {
        // stage x row into LDS: 64 lanes x float2 = 128 floats
        float2 v = ((const float2*)(x + (size_t)node * IN_DIM))[lane];
        ((float2*)xs[wv])[lane] = v;
    }
    __syncthreads();

    float acc = 0.f;
    if (valid) {
        #pragma unroll 8
        for (int k = 0; k < IN_DIM; ++k)
            acc += xs[wv][k] * W[k * OUT_DIM + lane];
        h[(size_t)node * OUT_DIM + lane] = acc;
    }

    float ps = valid ? acc * a_src[lane] : 0.f;
    float pt = valid ? acc * a_tgt[lane] : 0.f;
    #pragma unroll
    for (int off = 32; off; off >>= 1) {
        ps += __shfl_xor(ps, off);
        pt += __shfl_xor(pt, off);
    }
    if (valid && lane == 0) { hs[node] = ps; ht[node] = pt; }
}

// Order-preserving float->uint key: key(a) < key(b) iff a < b (for non-NaN).
// key(f) > 0 for every real float, so memset-0 init acts as -inf.
__device__ __forceinline__ unsigned fkey(float f) {
    unsigned b = __float_as_uint(f);
    return (b & 0x80000000u) ? ~b : (b | 0x80000000u);
}
__device__ __forceinline__ float fkey_dec(unsigned k) {
    unsigned b = (k & 0x80000000u) ? (k ^ 0x80000000u) : ~k;
    return __uint_as_float(b);
}

// ---------------- Kernel 2: per-edge logits + segment max -------------------
__global__ __launch_bounds__(256) void k_edge_logit(
    const int* __restrict__ src, const int* __restrict__ tgt,
    const float* __restrict__ ew, const float* __restrict__ hs,
    const float* __restrict__ ht, float* __restrict__ e,
    unsigned* __restrict__ emax_u, int ecount)
{
    int i = blockIdx.x * blockDim.x + threadIdx.x;
    if (i >= ecount) return;
    int s = src[i], t = tgt[i];
    float v = hs[s] + ht[t];
    v = (v > 0.f) ? v : 0.2f * v;          // leaky_relu, slope 0.2
    v *= ew[i];
    e[i] = v;
    atomicMax(emax_u + t, fkey(v));
}

// ---------------- Kernel 3: exp(e - max) + segment sum ----------------------
__global__ __launch_bounds__(256) void k_edge_exp(
    const int* __restrict__ tgt, float* __restrict__ e,
    const unsigned* __restrict__ emax_u, float* __restrict__ esum,
    int ecount)
{
    int i = blockIdx.x * blockDim.x + threadIdx.x;
    if (i >= ecount) return;
    int t = tgt[i];
    float m = fkey_dec(emax_u[t]);
    float ex = __expf(e[i] - m);
    e[i] = ex;                              // in place: e now holds e_exp
    unsafeAtomicAdd(esum + t, ex);
}

// ---------------- Kernel 4: out[tgt] += alpha * h[src] ----------------------
// One wave per edge; lane d handles dim d.
__global__ __launch_bounds__(256) void k_aggregate(
    const int* __restrict__ src, const int* __restrict__ tgt,
    const float* __restrict__ eexp, const float* __restrict__ esum,
    const float* __restrict__ h, float* __restrict__ out, int ecount)
{
    int edge = (int)((blockIdx.x * (unsigned)blockDim.x + threadIdx.x) >> 6);
    int lane = threadIdx.x & 63;
    if (edge >= ecount) return;
    int s = src[edge], t = tgt[edge];
    float alpha = eexp[edge] / (esum[t] + 1e-10f);
    float val = alpha * h[(size_t)s * OUT_DIM + lane];
    unsafeAtomicAdd(out + (size_t)t * OUT_DIM + lane, val);
}

extern "C" void kernel_launch(void* const* d_in, const int* in_sizes, int n_in,
                              void* d_out, int out_size, void* d_ws, size_t ws_size,
                              hipStream_t stream) {
    const float* x     = (const float*)d_in[0];
    const int*   eidx  = (const int*)d_in[1];
    const float* ew    = (const float*)d_in[2];
    const float* W     = (const float*)d_in[3];
    const float* a_src = (const float*)d_in[4];
    const float* a_tgt = (const float*)d_in[5];
    float* out = (float*)d_out;

    const int n = in_sizes[0] / IN_DIM;     // 100000
    const int E = in_sizes[2];              // 3200000
    const int* src = eidx;
    const int* tgt = eidx + E;

    // Workspace layout (floats):
    // h[n*64] | hs[n] | ht[n] | esum[n] | emax_u[n] | e[E]
    float* ws = (float*)d_ws;
    float*    h      = ws;                   ws += (size_t)n * OUT_DIM;
    float*    hs     = ws;                   ws += n;
    float*    ht     = ws;                   ws += n;
    float*    esum   = ws;                   ws += n;
    unsigned* emax_u = (unsigned*)ws;        ws += n;
    float*    e      = ws;                   ws += E;

    // Zero-init accumulators (harness poisons d_out/d_ws with 0xAA).
    hipMemsetAsync(d_out, 0, (size_t)out_size * sizeof(float), stream);
    hipMemsetAsync(esum, 0, (size_t)n * sizeof(float), stream);
    hipMemsetAsync(emax_u, 0, (size_t)n * sizeof(unsigned), stream);

    // K1: linear + attention logits per node
    k_linear<<<(n + 3) / 4, 256, 0, stream>>>(x, W, a_src, a_tgt, h, hs, ht, n);

    // K2: edge logits + segment max
    k_edge_logit<<<(E + 255) / 256, 256, 0, stream>>>(src, tgt, ew, hs, ht, e, emax_u, E);

    // K3: exp + segment sum
    k_edge_exp<<<(E + 255) / 256, 256, 0, stream>>>(tgt, e, emax_u, esum, E);

    // K4: weighted scatter-add aggregation (wave per edge)
    k_aggregate<<<(E + 63) / 64 * 64 * 64 / 256 /* = E/4 blocks */ , 256, 0, stream>>>(
        src, tgt, e, esum, h, out, E);
}

// Round 2
// 894.431 us; speedup vs baseline: 1.3631x; 1.3631x over previous
//
#include <hip/hip_runtime.h>
#include <hip/hip_bf16.h>

// GAT layer, CSR-sorted formulation: N=100000, E=3200000, IN=128, OUT=64.
// Strategy: counting-sort edges by tgt on the fly, then softmax+aggregate as
// per-node gather reductions -> zero float atomics, one write per out elem.

#define IN_DIM 128
#define OUT_DIM 64
#define SCAN_CHUNK 1024   // elements per scan block (256 thr x 4)

// ---------------- K1: h = x@W, hs = h.a_src, ht = h.a_tgt -------------------
// 4 nodes per wave (amortize W loads), 4 waves/block => 16 nodes/block.
__global__ __launch_bounds__(256) void k_linear(
    const float* __restrict__ x, const float* __restrict__ W,
    const float* __restrict__ a_src, const float* __restrict__ a_tgt,
    float* __restrict__ h, float* __restrict__ hs, float* __restrict__ ht,
    int n)
{
    __shared__ float xs[16][IN_DIM];
    const int lane  = threadIdx.x & 63;
    const int wv    = threadIdx.x >> 6;
    const int node0 = (blockIdx.x * 4 + wv) * 4;   // first of this wave's 4 nodes

    // Stage 4 x-rows (512 floats = 128 float4) into LDS, guarded per row.
    {
        const float4* s4 = (const float4*)(x + (size_t)node0 * IN_DIM);
        float4* d4 = (float4*)&xs[wv * 4][0];
        int nrows = n - node0;
        for (int i = lane; i < 128; i += 64) {
            int row = i >> 5;                       // 32 float4 per row
            float4 v = make_float4(0.f, 0.f, 0.f, 0.f);
            if (row < nrows) v = s4[i];
            d4[i] = v;
        }
    }
    __syncthreads();

    float acc[4] = {0.f, 0.f, 0.f, 0.f};
    const float* xr = &xs[wv * 4][0];
    #pragma unroll
    for (int kb = 0; kb < IN_DIM; kb += 4) {
        float4 x0 = *(const float4*)&xr[0 * IN_DIM + kb];
        float4 x1 = *(const float4*)&xr[1 * IN_DIM + kb];
        float4 x2 = *(const float4*)&xr[2 * IN_DIM + kb];
        float4 x3 = *(const float4*)&xr[3 * IN_DIM + kb];
        float w0 = W[(kb + 0) * OUT_DIM + lane];
        float w1 = W[(kb + 1) * OUT_DIM + lane];
        float w2 = W[(kb + 2) * OUT_DIM + lane];
        float w3 = W[(kb + 3) * OUT_DIM + lane];
        acc[0] += x0.x * w0 + x0.y * w1 + x0.z * w2 + x0.w * w3;
        acc[1] += x1.x * w0 + x1.y * w1 + x1.z * w2 + x1.w * w3;
        acc[2] += x2.x * w0 + x2.y * w1 + x2.z * w2 + x2.w * w3;
        acc[3] += x3.x * w0 + x3.y * w1 + x3.z * w2 + x3.w * w3;
    }

    #pragma unroll
    for (int r = 0; r < 4; ++r) {
        int node = node0 + r;
        float ps = acc[r] * a_src[lane];
        float pt = acc[r] * a_tgt[lane];
        #pragma unroll
        for (int off = 32; off; off >>= 1) {
            ps += __shfl_xor(ps, off);
            pt += __shfl_xor(pt, off);
        }
        if (node < n) {
            h[(size_t)node * OUT_DIM + lane] = acc[r];
            if (lane == 0) { hs[node] = ps; ht[node] = pt; }
        }
    }
}

// ---------------- K2: degree histogram -------------------------------------
__global__ __launch_bounds__(256) void k_hist(
    const int* __restrict__ tgt, int* __restrict__ cnt, int ecount)
{
    int i = blockIdx.x * blockDim.x + threadIdx.x;
    if (i < ecount) atomicAdd(cnt + tgt[i], 1);
}

// ---------------- K3a/b/c: exclusive scan of degrees -> rowptr --------------
__global__ __launch_bounds__(256) void k_scan1(
    const int* __restrict__ cnt, int* __restrict__ pre,
    int* __restrict__ bsum, int n)
{
    __shared__ int lds[256];
    const int tid = threadIdx.x;
    const int idx = blockIdx.x * SCAN_CHUNK + tid * 4;
    int4 v = make_int4(0, 0, 0, 0);
    if (idx + 3 < n) v = *(const int4*)(cnt + idx);
    else {
        if (idx + 0 < n) v.x = cnt[idx + 0];
        if (idx + 1 < n) v.y = cnt[idx + 1];
        if (idx + 2 < n) v.z = cnt[idx + 2];
        if (idx + 3 < n) v.w = cnt[idx + 3];
    }
    int tsum = v.x + v.y + v.z + v.w;
    lds[tid] = tsum;
    __syncthreads();
    for (int off = 1; off < 256; off <<= 1) {
        int val = (tid >= off) ? lds[tid - off] : 0;
        __syncthreads();
        lds[tid] += val;
        __syncthreads();
    }
    int excl = lds[tid] - tsum;
    if (tid == 255) bsum[blockIdx.x] = lds[255];
    int e0 = excl, e1 = e0 + v.x, e2 = e1 + v.y, e3 = e2 + v.z;
    if (idx + 0 < n) pre[idx + 0] = e0;
    if (idx + 1 < n) pre[idx + 1] = e1;
    if (idx + 2 < n) pre[idx + 2] = e2;
    if (idx + 3 < n) pre[idx + 3] = e3;
}

__global__ void k_scan2(int* __restrict__ bsum, int nb)
{
    if (threadIdx.x == 0 && blockIdx.x == 0) {
        int run = 0;
        for (int i = 0; i < nb; ++i) { int t = bsum[i]; bsum[i] = run; run += t; }
    }
}

// adds block offsets; writes final rowptr AND the fill-counter copy; sets rowptr[n]=E
__global__ __launch_bounds__(256) void k_scan3(
    int* __restrict__ rowptr, int* __restrict__ fill,
    const int* __restrict__ bsum, int n, int ecount)
{
    const int off = bsum[blockIdx.x];
    const int base = blockIdx.x * SCAN_CHUNK + threadIdx.x * 4;
    #pragma unroll
    for (int k = 0; k < 4; ++k) {
        int idx = base + k;
        if (idx < n) {
            int v = rowptr[idx] + off;
            rowptr[idx] = v;
            fill[idx]   = v;
        }
    }
    if (blockIdx.x == 0 && threadIdx.x == 0) rowptr[n] = ecount;
}

// ---------------- K4: fused edge-logit + counting-sort scatter --------------
__global__ __launch_bounds__(256) void k_scatter(
    const int* __restrict__ src, const int* __restrict__ tgt,
    const float* __restrict__ ew, const float* __restrict__ hs,
    const float* __restrict__ ht, int* __restrict__ fill,
    float2* __restrict__ edat, int ecount)
{
    int i = blockIdx.x * blockDim.x + threadIdx.x;
    if (i >= ecount) return;
    int s = src[i], t = tgt[i];
    float v = hs[s] + ht[t];
    v = (v > 0.f) ? v : 0.2f * v;          // leaky_relu slope 0.2
    v *= ew[i];
    int pos = atomicAdd(fill + t, 1);
    edat[pos] = make_float2(__int_as_float(s), v);
}

// ---------------- K5: per-node softmax + aggregation (no atomics) -----------
// One wave per target node. Phases 1-2: lanes over edges (max, sum-of-exp).
// Phase 3: lane = dim, sequential over edges, gather h[src] rows, 1 out write.
__global__ __launch_bounds__(256) void k_node(
    const int* __restrict__ rowptr, const float2* __restrict__ edat,
    const float* __restrict__ h, float* __restrict__ out, int n)
{
    const int lane = threadIdx.x & 63;
    const int wv   = threadIdx.x >> 6;
    const int t    = blockIdx.x * 4 + wv;
    if (t >= n) return;
    const int beg = rowptr[t], end = rowptr[t + 1];

    // phase 1: segment max
    float m = -INFINITY;
    for (int j = beg + lane; j < end; j += 64) m = fmaxf(m, edat[j].y);
    #pragma unroll
    for (int off = 32; off; off >>= 1) m = fmaxf(m, __shfl_xor(m, off));

    // phase 2: sum of exp
    float s = 0.f;
    for (int j = beg + lane; j < end; j += 64) s += __expf(edat[j].y - m);
    #pragma unroll
    for (int off = 32; off; off >>= 1) s += __shfl_xor(s, off);
    const float rden = 1.f / (s + 1e-10f);

    // phase 3: out[t][lane] = sum_j alpha_j * h[src_j][lane]
    float acc = 0.f;
    for (int j = beg; j < end; ++j) {
        float2 ed = edat[j];                       // uniform addr -> broadcast
        float coef = __expf(ed.y - m) * rden;
        int sidx = __float_as_int(ed.x);
        acc += coef * h[(size_t)sidx * OUT_DIM + lane];
    }
    out[(size_t)t * OUT_DIM + lane] = acc;
}

extern "C" void kernel_launch(void* const* d_in, const int* in_sizes, int n_in,
                              void* d_out, int out_size, void* d_ws, size_t ws_size,
                              hipStream_t stream) {
    const float* x     = (const float*)d_in[0];
    const int*   eidx  = (const int*)d_in[1];
    const float* ew    = (const float*)d_in[2];
    const float* W     = (const float*)d_in[3];
    const float* a_src = (const float*)d_in[4];
    const float* a_tgt = (const float*)d_in[5];
    float* out = (float*)d_out;

    const int n = in_sizes[0] / IN_DIM;     // 100000
    const int E = in_sizes[2];              // 3200000
    const int* src = eidx;
    const int* tgt = eidx + E;
    const int NB = (n + SCAN_CHUNK - 1) / SCAN_CHUNK;

    // Workspace layout (4-byte units, float2 buffer kept 8B-aligned):
    float* ws = (float*)d_ws;
    float* h      = ws;                 ws += (size_t)n * OUT_DIM;   // 6.4M
    float* hs     = ws;                 ws += n;
    float* ht     = ws;                 ws += n;
    int*   cnt    = (int*)ws;           ws += n;                     // hist, then fill
    int*   rowptr = (int*)ws;           ws += (n + 2);               // n+1, pad even
    int*   bsum   = (int*)ws;           ws += 128;
    float2* edat  = (float2*)ws;        // E pairs (src, e)

    hipMemsetAsync(cnt, 0, (size_t)n * sizeof(int), stream);

    k_linear<<<(n + 15) / 16, 256, 0, stream>>>(x, W, a_src, a_tgt, h, hs, ht, n);
    k_hist<<<(E + 255) / 256, 256, 0, stream>>>(tgt, cnt, E);
    k_scan1<<<NB, 256, 0, stream>>>(cnt, rowptr, bsum, n);
    k_scan2<<<1, 64, 0, stream>>>(bsum, NB);
    k_scan3<<<NB, 256, 0, stream>>>(rowptr, cnt, bsum, n, E);
    k_scatter<<<(E + 255) / 256, 256, 0, stream>>>(src, tgt, ew, hs, ht, cnt, edat, E);
    k_node<<<(n + 3) / 4, 256, 0, stream>>>(rowptr, edat, h, out, n);
}

// Round 3
// 716.575 us; speedup vs baseline: 1.7014x; 1.2482x over previous
//
#include <hip/hip_runtime.h>
#include <hip/hip_bf16.h>

// GAT layer, CSR-sorted formulation: N=100000, E=3200000, IN=128, OUT=64.
// R3: k_node 4x16 gather layout (4 edges in flight, float4 h-rows, unroll x2),
//     fused online-softmax (one fewer edat pass), parallel block-sum scan.

#define IN_DIM 128
#define OUT_DIM 64
#define SCAN_CHUNK 1024   // elements per scan block (256 thr x 4)

// ---------------- K1: h = x@W, hs = h.a_src, ht = h.a_tgt -------------------
// 4 nodes per wave (amortize W loads), 4 waves/block => 16 nodes/block.
__global__ __launch_bounds__(256) void k_linear(
    const float* __restrict__ x, const float* __restrict__ W,
    const float* __restrict__ a_src, const float* __restrict__ a_tgt,
    float* __restrict__ h, float* __restrict__ hs, float* __restrict__ ht,
    int n)
{
    __shared__ float xs[16][IN_DIM];
    const int lane  = threadIdx.x & 63;
    const int wv    = threadIdx.x >> 6;
    const int node0 = (blockIdx.x * 4 + wv) * 4;

    {
        const float4* s4 = (const float4*)(x + (size_t)node0 * IN_DIM);
        float4* d4 = (float4*)&xs[wv * 4][0];
        int nrows = n - node0;
        for (int i = lane; i < 128; i += 64) {
            int row = i >> 5;                       // 32 float4 per row
            float4 v = make_float4(0.f, 0.f, 0.f, 0.f);
            if (row < nrows) v = s4[i];
            d4[i] = v;
        }
    }
    __syncthreads();

    float acc[4] = {0.f, 0.f, 0.f, 0.f};
    const float* xr = &xs[wv * 4][0];
    #pragma unroll
    for (int kb = 0; kb < IN_DIM; kb += 4) {
        float4 x0 = *(const float4*)&xr[0 * IN_DIM + kb];
        float4 x1 = *(const float4*)&xr[1 * IN_DIM + kb];
        float4 x2 = *(const float4*)&xr[2 * IN_DIM + kb];
        float4 x3 = *(const float4*)&xr[3 * IN_DIM + kb];
        float w0 = W[(kb + 0) * OUT_DIM + lane];
        float w1 = W[(kb + 1) * OUT_DIM + lane];
        float w2 = W[(kb + 2) * OUT_DIM + lane];
        float w3 = W[(kb + 3) * OUT_DIM + lane];
        acc[0] += x0.x * w0 + x0.y * w1 + x0.z * w2 + x0.w * w3;
        acc[1] += x1.x * w0 + x1.y * w1 + x1.z * w2 + x1.w * w3;
        acc[2] += x2.x * w0 + x2.y * w1 + x2.z * w2 + x2.w * w3;
        acc[3] += x3.x * w0 + x3.y * w1 + x3.z * w2 + x3.w * w3;
    }

    #pragma unroll
    for (int r = 0; r < 4; ++r) {
        int node = node0 + r;
        float ps = acc[r] * a_src[lane];
        float pt = acc[r] * a_tgt[lane];
        #pragma unroll
        for (int off = 32; off; off >>= 1) {
            ps += __shfl_xor(ps, off);
            pt += __shfl_xor(pt, off);
        }
        if (node < n) {
            h[(size_t)node * OUT_DIM + lane] = acc[r];
            if (lane == 0) { hs[node] = ps; ht[node] = pt; }
        }
    }
}

// ---------------- K2: degree histogram -------------------------------------
__global__ __launch_bounds__(256) void k_hist(
    const int* __restrict__ tgt, int* __restrict__ cnt, int ecount)
{
    int i = blockIdx.x * blockDim.x + threadIdx.x;
    if (i < ecount) atomicAdd(cnt + tgt[i], 1);
}

// ---------------- K3a/b/c: exclusive scan of degrees -> rowptr --------------
__global__ __launch_bounds__(256) void k_scan1(
    const int* __restrict__ cnt, int* __restrict__ pre,
    int* __restrict__ bsum, int n)
{
    __shared__ int lds[256];
    const int tid = threadIdx.x;
    const int idx = blockIdx.x * SCAN_CHUNK + tid * 4;
    int4 v = make_int4(0, 0, 0, 0);
    if (idx + 3 < n) v = *(const int4*)(cnt + idx);
    else {
        if (idx + 0 < n) v.x = cnt[idx + 0];
        if (idx + 1 < n) v.y = cnt[idx + 1];
        if (idx + 2 < n) v.z = cnt[idx + 2];
        if (idx + 3 < n) v.w = cnt[idx + 3];
    }
    int tsum = v.x + v.y + v.z + v.w;
    lds[tid] = tsum;
    __syncthreads();
    for (int off = 1; off < 256; off <<= 1) {
        int val = (tid >= off) ? lds[tid - off] : 0;
        __syncthreads();
        lds[tid] += val;
        __syncthreads();
    }
    int excl = lds[tid] - tsum;
    if (tid == 255) bsum[blockIdx.x] = lds[255];
    int e0 = excl, e1 = e0 + v.x, e2 = e1 + v.y, e3 = e2 + v.z;
    if (idx + 0 < n) pre[idx + 0] = e0;
    if (idx + 1 < n) pre[idx + 1] = e1;
    if (idx + 2 < n) pre[idx + 2] = e2;
    if (idx + 3 < n) pre[idx + 3] = e3;
}

// parallel exclusive scan of up to 128 block sums, single wave
__global__ void k_scan2(int* __restrict__ bsum, int nb)
{
    const int lane = threadIdx.x;    // 64 threads
    int v0 = (lane      < nb) ? bsum[lane]      : 0;
    int v1 = (lane + 64 < nb) ? bsum[lane + 64] : 0;
    int t0 = v0;
    #pragma unroll
    for (int off = 1; off < 64; off <<= 1) {
        int u = __shfl_up(t0, off);
        if (lane >= off) t0 += u;
    }
    int total0 = __shfl(t0, 63);
    int t1 = v1;
    #pragma unroll
    for (int off = 1; off < 64; off <<= 1) {
        int u = __shfl_up(t1, off);
        if (lane >= off) t1 += u;
    }
    t1 += total0;
    if (lane      < nb) bsum[lane]      = t0 - v0;
    if (lane + 64 < nb) bsum[lane + 64] = t1 - v1;
}

// adds block offsets; writes final rowptr AND the fill-counter copy; rowptr[n]=E
__global__ __launch_bounds__(256) void k_scan3(
    int* __restrict__ rowptr, int* __restrict__ fill,
    const int* __restrict__ bsum, int n, int ecount)
{
    const int off = bsum[blockIdx.x];
    const int base = blockIdx.x * SCAN_CHUNK + threadIdx.x * 4;
    #pragma unroll
    for (int k = 0; k < 4; ++k) {
        int idx = base + k;
        if (idx < n) {
            int v = rowptr[idx] + off;
            rowptr[idx] = v;
            fill[idx]   = v;
        }
    }
    if (blockIdx.x == 0 && threadIdx.x == 0) rowptr[n] = ecount;
}

// ---------------- K4: fused edge-logit + counting-sort scatter --------------
__global__ __launch_bounds__(256) void k_scatter(
    const int* __restrict__ src, const int* __restrict__ tgt,
    const float* __restrict__ ew, const float* __restrict__ hs,
    const float* __restrict__ ht, int* __restrict__ fill,
    float2* __restrict__ edat, int ecount)
{
    int i = blockIdx.x * blockDim.x + threadIdx.x;
    if (i >= ecount) return;
    int s = src[i], t = tgt[i];
    float v = hs[s] + ht[t];
    v = (v > 0.f) ? v : 0.2f * v;          // leaky_relu slope 0.2
    v *= ew[i];
    int pos = atomicAdd(fill + t, 1);
    edat[pos] = make_float2(__int_as_float(s), v);
}

// guarded exp for online-softmax merges: maps NaN (from -inf - -inf) to ~0
__device__ __forceinline__ float expg(float d) {
    return __expf(fmaxf(d, -80.f));
}

// ---------------- K5: per-node softmax + aggregation (no atomics) -----------
// One wave per target node. Phase A: fused online max+sum over edges.
// Phase B: 4 groups x 16 lanes; group = edge, lane = 4 dims (float4 gather).
__global__ __launch_bounds__(256) void k_node(
    const int* __restrict__ rowptr, const float2* __restrict__ edat,
    const float* __restrict__ h, float* __restrict__ out, int n)
{
    const int lane = threadIdx.x & 63;
    const int wv   = threadIdx.x >> 6;
    const int t    = blockIdx.x * 4 + wv;
    if (t >= n) return;
    const int beg = rowptr[t], end = rowptr[t + 1];

    // Phase A: online softmax (max + sum-of-exp in one pass)
    float m = -INFINITY, s = 0.f;
    for (int j = beg + lane; j < end; j += 64) {
        float v = edat[j].y;
        float nm = fmaxf(m, v);
        s = s * expg(m - nm) + expg(v - nm);
        m = nm;
    }
    #pragma unroll
    for (int off = 32; off; off >>= 1) {
        float mo = __shfl_xor(m, off);
        float so = __shfl_xor(s, off);
        float nm = fmaxf(m, mo);
        s = s * expg(m - nm) + so * expg(mo - nm);
        m = nm;
    }
    const float rden = 1.f / (s + 1e-10f);

    // Phase B: out[t][:] = sum_j alpha_j * h[src_j][:], 4 edges in flight x2
    const int g  = lane >> 4;        // group 0..3 -> edge j+g
    const int l4 = lane & 15;        // 4 dims per lane
    float4 a0 = make_float4(0.f, 0.f, 0.f, 0.f);
    float4 a1 = make_float4(0.f, 0.f, 0.f, 0.f);
    int j = beg;
    for (; j + 8 <= end; j += 8) {
        float2 e0 = edat[j + g];
        float2 e1 = edat[j + 4 + g];
        int s0 = __float_as_int(e0.x);
        int s1 = __float_as_int(e1.x);
        float4 h0 = ((const float4*)(h + (size_t)s0 * OUT_DIM))[l4];
        float4 h1 = ((const float4*)(h + (size_t)s1 * OUT_DIM))[l4];
        float c0 = __expf(e0.y - m) * rden;
        float c1 = __expf(e1.y - m) * rden;
        a0.x += c0 * h0.x; a0.y += c0 * h0.y; a0.z += c0 * h0.z; a0.w += c0 * h0.w;
        a1.x += c1 * h1.x; a1.y += c1 * h1.y; a1.z += c1 * h1.z; a1.w += c1 * h1.w;
    }
    for (; j < end; j += 4) {
        int jj = j + g;
        bool valid = jj < end;
        float2 ed = edat[valid ? jj : (end - 1)];
        int sidx = __float_as_int(ed.x);
        float4 hv = ((const float4*)(h + (size_t)sidx * OUT_DIM))[l4];
        float c = valid ? __expf(ed.y - m) * rden : 0.f;
        a0.x += c * hv.x; a0.y += c * hv.y; a0.z += c * hv.z; a0.w += c * hv.w;
    }
    a0.x += a1.x; a0.y += a1.y; a0.z += a1.z; a0.w += a1.w;

    // reduce across the 4 groups (lanes l4, l4+16, l4+32, l4+48)
    #pragma unroll
    for (int off = 32; off >= 16; off >>= 1) {
        a0.x += __shfl_xor(a0.x, off);
        a0.y += __shfl_xor(a0.y, off);
        a0.z += __shfl_xor(a0.z, off);
        a0.w += __shfl_xor(a0.w, off);
    }
    if (g == 0)
        ((float4*)(out + (size_t)t * OUT_DIM))[l4] = a0;
}

extern "C" void kernel_launch(void* const* d_in, const int* in_sizes, int n_in,
                              void* d_out, int out_size, void* d_ws, size_t ws_size,
                              hipStream_t stream) {
    const float* x     = (const float*)d_in[0];
    const int*   eidx  = (const int*)d_in[1];
    const float* ew    = (const float*)d_in[2];
    const float* W     = (const float*)d_in[3];
    const float* a_src = (const float*)d_in[4];
    const float* a_tgt = (const float*)d_in[5];
    float* out = (float*)d_out;

    const int n = in_sizes[0] / IN_DIM;     // 100000
    const int E = in_sizes[2];              // 3200000
    const int* src = eidx;
    const int* tgt = eidx + E;
    const int NB = (n + SCAN_CHUNK - 1) / SCAN_CHUNK;

    float* ws = (float*)d_ws;
    float* h      = ws;                 ws += (size_t)n * OUT_DIM;
    float* hs     = ws;                 ws += n;
    float* ht     = ws;                 ws += n;
    int*   cnt    = (int*)ws;           ws += n;                  // hist, then fill
    int*   rowptr = (int*)ws;           ws += (n + 2);
    int*   bsum   = (int*)ws;           ws += 128;
    float2* edat  = (float2*)ws;        // E pairs (src, e)

    hipMemsetAsync(cnt, 0, (size_t)n * sizeof(int), stream);

    k_linear<<<(n + 15) / 16, 256, 0, stream>>>(x, W, a_src, a_tgt, h, hs, ht, n);
    k_hist<<<(E + 255) / 256, 256, 0, stream>>>(tgt, cnt, E);
    k_scan1<<<NB, 256, 0, stream>>>(cnt, rowptr, bsum, n);
    k_scan2<<<1, 64, 0, stream>>>(bsum, NB);
    k_scan3<<<NB, 256, 0, stream>>>(rowptr, cnt, bsum, n, E);
    k_scatter<<<(E + 255) / 256, 256, 0, stream>>>(src, tgt, ew, hs, ht, cnt, edat, E);
    k_node<<<(n + 3) / 4, 256, 0, stream>>>(rowptr, edat, h, out, n);
}

// Round 4
// 553.591 us; speedup vs baseline: 2.2024x; 1.2944x over previous
//
#include <hip/hip_runtime.h>
#include <hip/hip_bf16.h>

// GAT layer, CSR-sorted formulation: N=100000, E=3200000, IN=128, OUT=64.
// R4: k_linear rebuilt as LDS-tiled fp32 GEMM (512 thr, 64 nodes/block,
//     W + x-tile in LDS, 8 float4 acc/thread) -- fixes the 256-VGPR /
//     11%-occupancy latency bind from R2/R3.

#define IN_DIM 128
#define OUT_DIM 64
#define SCAN_CHUNK 1024   // elements per scan block (256 thr x 4)
#define LNODES 64         // nodes per k_linear block

// ---------------- K1: h = x@W, hs = h.a_src, ht = h.a_tgt -------------------
// 512 threads: lane16 = tid&15 -> 4 dims (float4), mrow = tid>>4 in [0,32)
// -> nodes mrow, mrow+32. W and x-tile staged in LDS.
__global__ __launch_bounds__(512) void k_linear(
    const float* __restrict__ x, const float* __restrict__ W,
    const float* __restrict__ a_src, const float* __restrict__ a_tgt,
    float* __restrict__ h, float* __restrict__ hs, float* __restrict__ ht,
    int n)
{
    __shared__ float ws_W[IN_DIM][OUT_DIM];        // 32 KB, original [k][dim]
    __shared__ float xs[LNODES][IN_DIM + 4];       // padded rows: 33 KB
    const int tid   = threadIdx.x;
    const int node0 = blockIdx.x * LNODES;

    // stage W: 2048 float4 over 512 threads
    {
        const float4* Wsrc = (const float4*)W;
        float4* Wdst = (float4*)&ws_W[0][0];
        #pragma unroll
        for (int i = 0; i < 4; ++i) Wdst[tid + 512 * i] = Wsrc[tid + 512 * i];
    }
    // stage x tile: nrows x 128 floats (32 float4 per row), coalesced
    {
        int nrows = n - node0; if (nrows > LNODES) nrows = LNODES;
        for (int i = tid; i < nrows * 32; i += 512) {
            int r = i >> 5, c4 = i & 31;
            float4 v = ((const float4*)(x + (size_t)(node0 + r) * IN_DIM))[c4];
            *(float4*)&xs[r][c4 * 4] = v;
        }
    }
    __syncthreads();

    const int lane16 = tid & 15;          // dim group: d0 = lane16*4
    const int mrow   = tid >> 4;          // 0..31
    float4 acc[2];
    acc[0] = make_float4(0.f, 0.f, 0.f, 0.f);
    acc[1] = make_float4(0.f, 0.f, 0.f, 0.f);

    #pragma unroll 2
    for (int k = 0; k < IN_DIM; k += 4) {
        float4 w0 = *(const float4*)&ws_W[k + 0][lane16 * 4];
        float4 w1 = *(const float4*)&ws_W[k + 1][lane16 * 4];
        float4 w2 = *(const float4*)&ws_W[k + 2][lane16 * 4];
        float4 w3 = *(const float4*)&ws_W[k + 3][lane16 * 4];
        #pragma unroll
        for (int u = 0; u < 2; ++u) {
            float4 xv = *(const float4*)&xs[mrow + 32 * u][k];
            acc[u].x += w0.x * xv.x + w1.x * xv.y + w2.x * xv.z + w3.x * xv.w;
            acc[u].y += w0.y * xv.x + w1.y * xv.y + w2.y * xv.z + w3.y * xv.w;
            acc[u].z += w0.z * xv.x + w1.z * xv.y + w2.z * xv.z + w3.z * xv.w;
            acc[u].w += w0.w * xv.x + w1.w * xv.y + w2.w * xv.z + w3.w * xv.w;
        }
    }

    const float4 as = ((const float4*)a_src)[lane16];
    const float4 at = ((const float4*)a_tgt)[lane16];
    #pragma unroll
    for (int u = 0; u < 2; ++u) {
        int node = node0 + mrow + 32 * u;
        float ps = acc[u].x * as.x + acc[u].y * as.y + acc[u].z * as.z + acc[u].w * as.w;
        float pt = acc[u].x * at.x + acc[u].y * at.y + acc[u].z * at.z + acc[u].w * at.w;
        #pragma unroll
        for (int off = 8; off; off >>= 1) {       // reduce across the 16 dim-lanes
            ps += __shfl_xor(ps, off);
            pt += __shfl_xor(pt, off);
        }
        if (node < n) {
            ((float4*)(h + (size_t)node * OUT_DIM))[lane16] = acc[u];
            if (lane16 == 0) { hs[node] = ps; ht[node] = pt; }
        }
    }
}

// ---------------- K2: degree histogram -------------------------------------
__global__ __launch_bounds__(256) void k_hist(
    const int* __restrict__ tgt, int* __restrict__ cnt, int ecount)
{
    int i = blockIdx.x * blockDim.x + threadIdx.x;
    if (i < ecount) atomicAdd(cnt + tgt[i], 1);
}

// ---------------- K3a/b/c: exclusive scan of degrees -> rowptr --------------
__global__ __launch_bounds__(256) void k_scan1(
    const int* __restrict__ cnt, int* __restrict__ pre,
    int* __restrict__ bsum, int n)
{
    __shared__ int lds[256];
    const int tid = threadIdx.x;
    const int idx = blockIdx.x * SCAN_CHUNK + tid * 4;
    int4 v = make_int4(0, 0, 0, 0);
    if (idx + 3 < n) v = *(const int4*)(cnt + idx);
    else {
        if (idx + 0 < n) v.x = cnt[idx + 0];
        if (idx + 1 < n) v.y = cnt[idx + 1];
        if (idx + 2 < n) v.z = cnt[idx + 2];
        if (idx + 3 < n) v.w = cnt[idx + 3];
    }
    int tsum = v.x + v.y + v.z + v.w;
    lds[tid] = tsum;
    __syncthreads();
    for (int off = 1; off < 256; off <<= 1) {
        int val = (tid >= off) ? lds[tid - off] : 0;
        __syncthreads();
        lds[tid] += val;
        __syncthreads();
    }
    int excl = lds[tid] - tsum;
    if (tid == 255) bsum[blockIdx.x] = lds[255];
    int e0 = excl, e1 = e0 + v.x, e2 = e1 + v.y, e3 = e2 + v.z;
    if (idx + 0 < n) pre[idx + 0] = e0;
    if (idx + 1 < n) pre[idx + 1] = e1;
    if (idx + 2 < n) pre[idx + 2] = e2;
    if (idx + 3 < n) pre[idx + 3] = e3;
}

// parallel exclusive scan of up to 128 block sums, single wave
__global__ void k_scan2(int* __restrict__ bsum, int nb)
{
    const int lane = threadIdx.x;    // 64 threads
    int v0 = (lane      < nb) ? bsum[lane]      : 0;
    int v1 = (lane + 64 < nb) ? bsum[lane + 64] : 0;
    int t0 = v0;
    #pragma unroll
    for (int off = 1; off < 64; off <<= 1) {
        int u = __shfl_up(t0, off);
        if (lane >= off) t0 += u;
    }
    int total0 = __shfl(t0, 63);
    int t1 = v1;
    #pragma unroll
    for (int off = 1; off < 64; off <<= 1) {
        int u = __shfl_up(t1, off);
        if (lane >= off) t1 += u;
    }
    t1 += total0;
    if (lane      < nb) bsum[lane]      = t0 - v0;
    if (lane + 64 < nb) bsum[lane + 64] = t1 - v1;
}

// adds block offsets; writes final rowptr AND the fill-counter copy; rowptr[n]=E
__global__ __launch_bounds__(256) void k_scan3(
    int* __restrict__ rowptr, int* __restrict__ fill,
    const int* __restrict__ bsum, int n, int ecount)
{
    const int off = bsum[blockIdx.x];
    const int base = blockIdx.x * SCAN_CHUNK + threadIdx.x * 4;
    #pragma unroll
    for (int k = 0; k < 4; ++k) {
        int idx = base + k;
        if (idx < n) {
            int v = rowptr[idx] + off;
            rowptr[idx] = v;
            fill[idx]   = v;
        }
    }
    if (blockIdx.x == 0 && threadIdx.x == 0) rowptr[n] = ecount;
}

// ---------------- K4: fused edge-logit + counting-sort scatter --------------
__global__ __launch_bounds__(256) void k_scatter(
    const int* __restrict__ src, const int* __restrict__ tgt,
    const float* __restrict__ ew, const float* __restrict__ hs,
    const float* __restrict__ ht, int* __restrict__ fill,
    float2* __restrict__ edat, int ecount)
{
    int i = blockIdx.x * blockDim.x + threadIdx.x;
    if (i >= ecount) return;
    int s = src[i], t = tgt[i];
    float v = hs[s] + ht[t];
    v = (v > 0.f) ? v : 0.2f * v;          // leaky_relu slope 0.2
    v *= ew[i];
    int pos = atomicAdd(fill + t, 1);
    edat[pos] = make_float2(__int_as_float(s), v);
}

// guarded exp for online-softmax merges: maps NaN (from -inf - -inf) to ~0
__device__ __forceinline__ float expg(float d) {
    return __expf(fmaxf(d, -80.f));
}

// ---------------- K5: per-node softmax + aggregation (no atomics) -----------
// One wave per target node. Phase A: fused online max+sum over edges.
// Phase B: 4 groups x 16 lanes; group = edge, lane = 4 dims (float4 gather).
__global__ __launch_bounds__(256) void k_node(
    const int* __restrict__ rowptr, const float2* __restrict__ edat,
    const float* __restrict__ h, float* __restrict__ out, int n)
{
    const int lane = threadIdx.x & 63;
    const int wv   = threadIdx.x >> 6;
    const int t    = blockIdx.x * 4 + wv;
    if (t >= n) return;
    const int beg = rowptr[t], end = rowptr[t + 1];

    // Phase A: online softmax (max + sum-of-exp in one pass)
    float m = -INFINITY, s = 0.f;
    for (int j = beg + lane; j < end; j += 64) {
        float v = edat[j].y;
        float nm = fmaxf(m, v);
        s = s * expg(m - nm) + expg(v - nm);
        m = nm;
    }
    #pragma unroll
    for (int off = 32; off; off >>= 1) {
        float mo = __shfl_xor(m, off);
        float so = __shfl_xor(s, off);
        float nm = fmaxf(m, mo);
        s = s * expg(m - nm) + so * expg(mo - nm);
        m = nm;
    }
    const float rden = 1.f / (s + 1e-10f);

    // Phase B: out[t][:] = sum_j alpha_j * h[src_j][:], 4 edges in flight x2
    const int g  = lane >> 4;        // group 0..3 -> edge j+g
    const int l4 = lane & 15;        // 4 dims per lane
    float4 a0 = make_float4(0.f, 0.f, 0.f, 0.f);
    float4 a1 = make_float4(0.f, 0.f, 0.f, 0.f);
    int j = beg;
    for (; j + 8 <= end; j += 8) {
        float2 e0 = edat[j + g];
        float2 e1 = edat[j + 4 + g];
        int s0 = __float_as_int(e0.x);
        int s1 = __float_as_int(e1.x);
        float4 h0 = ((const float4*)(h + (size_t)s0 * OUT_DIM))[l4];
        float4 h1 = ((const float4*)(h + (size_t)s1 * OUT_DIM))[l4];
        float c0 = __expf(e0.y - m) * rden;
        float c1 = __expf(e1.y - m) * rden;
        a0.x += c0 * h0.x; a0.y += c0 * h0.y; a0.z += c0 * h0.z; a0.w += c0 * h0.w;
        a1.x += c1 * h1.x; a1.y += c1 * h1.y; a1.z += c1 * h1.z; a1.w += c1 * h1.w;
    }
    for (; j < end; j += 4) {
        int jj = j + g;
        bool valid = jj < end;
        float2 ed = edat[valid ? jj : (end - 1)];
        int sidx = __float_as_int(ed.x);
        float4 hv = ((const float4*)(h + (size_t)sidx * OUT_DIM))[l4];
        float c = valid ? __expf(ed.y - m) * rden : 0.f;
        a0.x += c * hv.x; a0.y += c * hv.y; a0.z += c * hv.z; a0.w += c * hv.w;
    }
    a0.x += a1.x; a0.y += a1.y; a0.z += a1.z; a0.w += a1.w;

    // reduce across the 4 groups (lanes l4, l4+16, l4+32, l4+48)
    #pragma unroll
    for (int off = 32; off >= 16; off >>= 1) {
        a0.x += __shfl_xor(a0.x, off);
        a0.y += __shfl_xor(a0.y, off);
        a0.z += __shfl_xor(a0.z, off);
        a0.w += __shfl_xor(a0.w, off);
    }
    if (g == 0)
        ((float4*)(out + (size_t)t * OUT_DIM))[l4] = a0;
}

extern "C" void kernel_launch(void* const* d_in, const int* in_sizes, int n_in,
                              void* d_out, int out_size, void* d_ws, size_t ws_size,
                              hipStream_t stream) {
    const float* x     = (const float*)d_in[0];
    const int*   eidx  = (const int*)d_in[1];
    const float* ew    = (const float*)d_in[2];
    const float* W     = (const float*)d_in[3];
    const float* a_src = (const float*)d_in[4];
    const float* a_tgt = (const float*)d_in[5];
    float* out = (float*)d_out;

    const int n = in_sizes[0] / IN_DIM;     // 100000
    const int E = in_sizes[2];              // 3200000
    const int* src = eidx;
    const int* tgt = eidx + E;
    const int NB = (n + SCAN_CHUNK - 1) / SCAN_CHUNK;

    float* ws = (float*)d_ws;
    float* h      = ws;                 ws += (size_t)n * OUT_DIM;
    float* hs     = ws;                 ws += n;
    float* ht     = ws;                 ws += n;
    int*   cnt    = (int*)ws;           ws += n;                  // hist, then fill
    int*   rowptr = (int*)ws;           ws += (n + 2);
    int*   bsum   = (int*)ws;           ws += 128;
    float2* edat  = (float2*)ws;        // E pairs (src, e)

    hipMemsetAsync(cnt, 0, (size_t)n * sizeof(int), stream);

    k_linear<<<(n + LNODES - 1) / LNODES, 512, 0, stream>>>(x, W, a_src, a_tgt, h, hs, ht, n);
    k_hist<<<(E + 255) / 256, 256, 0, stream>>>(tgt, cnt, E);
    k_scan1<<<NB, 256, 0, stream>>>(cnt, rowptr, bsum, n);
    k_scan2<<<1, 64, 0, stream>>>(bsum, NB);
    k_scan3<<<NB, 256, 0, stream>>>(rowptr, cnt, bsum, n, E);
    k_scatter<<<(E + 255) / 256, 256, 0, stream>>>(src, tgt, ew, hs, ht, cnt, edat, E);
    k_node<<<(n + 3) / 4, 256, 0, stream>>>(rowptr, edat, h, out, n);
}

// Round 8
// 516.086 us; speedup vs baseline: 2.3624x; 1.0727x over previous
//
#include <hip/hip_runtime.h>
#include <hip/hip_bf16.h>

// GAT layer, CSR-sorted formulation: N=100000, E=3200000, IN=128, OUT=64.
// R8: identical resubmission of R7 (R4-proven structure + bf16 h) as an
//     infra-vs-code discriminating experiment. R7 is R4 (passed, 554us) with
//     one audited delta and a SMALLER workspace (40MB < proven 52.8MB); three
//     different codebases (R5/R6/R7) all dying without counters points at
//     container flakiness, not this code. If this fails too, R9 reverts to
//     exact R4.

#define IN_DIM 128
#define OUT_DIM 64
#define SCAN_CHUNK 1024   // elements per scan block (256 thr x 4)
#define LNODES 64         // nodes per k_linear block

// bf16 helpers (manual, round-to-nearest-even; no NaN expected here)
__device__ __forceinline__ unsigned short f2bf(float f) {
    unsigned u = __float_as_uint(f);
    return (unsigned short)((u + 0x7FFFu + ((u >> 16) & 1u)) >> 16);
}
__device__ __forceinline__ float bf2f(unsigned short u) {
    return __uint_as_float((unsigned)u << 16);
}

// ---------------- K1: h = x@W (bf16 out), hs = h.a_src, ht = h.a_tgt --------
// 512 threads: lane16 = tid&15 -> 4 dims (float4), mrow = tid>>4 in [0,32)
// -> nodes mrow, mrow+32. W and x-tile staged in LDS. (R4-proven structure.)
__global__ __launch_bounds__(512) void k_linear(
    const float* __restrict__ x, const float* __restrict__ W,
    const float* __restrict__ a_src, const float* __restrict__ a_tgt,
    unsigned short* __restrict__ hh, float* __restrict__ hs,
    float* __restrict__ ht, int n)
{
    __shared__ float ws_W[IN_DIM][OUT_DIM];        // 32 KB, original [k][dim]
    __shared__ float xs[LNODES][IN_DIM + 4];       // padded rows: 33 KB
    const int tid   = threadIdx.x;
    const int node0 = blockIdx.x * LNODES;

    {
        const float4* Wsrc = (const float4*)W;
        float4* Wdst = (float4*)&ws_W[0][0];
        #pragma unroll
        for (int i = 0; i < 4; ++i) Wdst[tid + 512 * i] = Wsrc[tid + 512 * i];
    }
    {
        int nrows = n - node0; if (nrows > LNODES) nrows = LNODES;
        for (int i = tid; i < nrows * 32; i += 512) {
            int r = i >> 5, c4 = i & 31;
            float4 v = ((const float4*)(x + (size_t)(node0 + r) * IN_DIM))[c4];
            *(float4*)&xs[r][c4 * 4] = v;
        }
    }
    __syncthreads();

    const int lane16 = tid & 15;
    const int mrow   = tid >> 4;
    float4 acc[2];
    acc[0] = make_float4(0.f, 0.f, 0.f, 0.f);
    acc[1] = make_float4(0.f, 0.f, 0.f, 0.f);

    #pragma unroll 2
    for (int k = 0; k < IN_DIM; k += 4) {
        float4 w0 = *(const float4*)&ws_W[k + 0][lane16 * 4];
        float4 w1 = *(const float4*)&ws_W[k + 1][lane16 * 4];
        float4 w2 = *(const float4*)&ws_W[k + 2][lane16 * 4];
        float4 w3 = *(const float4*)&ws_W[k + 3][lane16 * 4];
        #pragma unroll
        for (int u = 0; u < 2; ++u) {
            float4 xv = *(const float4*)&xs[mrow + 32 * u][k];
            acc[u].x += w0.x * xv.x + w1.x * xv.y + w2.x * xv.z + w3.x * xv.w;
            acc[u].y += w0.y * xv.x + w1.y * xv.y + w2.y * xv.z + w3.y * xv.w;
            acc[u].z += w0.z * xv.x + w1.z * xv.y + w2.z * xv.z + w3.z * xv.w;
            acc[u].w += w0.w * xv.x + w1.w * xv.y + w2.w * xv.z + w3.w * xv.w;
        }
    }

    const float4 as = ((const float4*)a_src)[lane16];
    const float4 at = ((const float4*)a_tgt)[lane16];
    #pragma unroll
    for (int u = 0; u < 2; ++u) {
        int node = node0 + mrow + 32 * u;
        float ps = acc[u].x * as.x + acc[u].y * as.y + acc[u].z * as.z + acc[u].w * as.w;
        float pt = acc[u].x * at.x + acc[u].y * at.y + acc[u].z * at.z + acc[u].w * at.w;
        #pragma unroll
        for (int off = 8; off; off >>= 1) {
            ps += __shfl_xor(ps, off);
            pt += __shfl_xor(pt, off);
        }
        if (node < n) {
            ushort4 hv;
            hv.x = f2bf(acc[u].x); hv.y = f2bf(acc[u].y);
            hv.z = f2bf(acc[u].z); hv.w = f2bf(acc[u].w);
            ((ushort4*)(hh + (size_t)node * OUT_DIM))[lane16] = hv;
            if (lane16 == 0) { hs[node] = ps; ht[node] = pt; }
        }
    }
}

// ---------------- K2: degree histogram -------------------------------------
__global__ __launch_bounds__(256) void k_hist(
    const int* __restrict__ tgt, int* __restrict__ cnt, int ecount)
{
    int i = blockIdx.x * blockDim.x + threadIdx.x;
    if (i < ecount) atomicAdd(cnt + tgt[i], 1);
}

// ---------------- K3a/b/c: exclusive scan of degrees -> rowptr --------------
__global__ __launch_bounds__(256) void k_scan1(
    const int* __restrict__ cnt, int* __restrict__ pre,
    int* __restrict__ bsum, int n)
{
    __shared__ int lds[256];
    const int tid = threadIdx.x;
    const int idx = blockIdx.x * SCAN_CHUNK + tid * 4;
    int4 v = make_int4(0, 0, 0, 0);
    if (idx + 3 < n) v = *(const int4*)(cnt + idx);
    else {
        if (idx + 0 < n) v.x = cnt[idx + 0];
        if (idx + 1 < n) v.y = cnt[idx + 1];
        if (idx + 2 < n) v.z = cnt[idx + 2];
        if (idx + 3 < n) v.w = cnt[idx + 3];
    }
    int tsum = v.x + v.y + v.z + v.w;
    lds[tid] = tsum;
    __syncthreads();
    for (int off = 1; off < 256; off <<= 1) {
        int val = (tid >= off) ? lds[tid - off] : 0;
        __syncthreads();
        lds[tid] += val;
        __syncthreads();
    }
    int excl = lds[tid] - tsum;
    if (tid == 255) bsum[blockIdx.x] = lds[255];
    int e0 = excl, e1 = e0 + v.x, e2 = e1 + v.y, e3 = e2 + v.z;
    if (idx + 0 < n) pre[idx + 0] = e0;
    if (idx + 1 < n) pre[idx + 1] = e1;
    if (idx + 2 < n) pre[idx + 2] = e2;
    if (idx + 3 < n) pre[idx + 3] = e3;
}

// parallel exclusive scan of up to 128 block sums, single wave
__global__ void k_scan2(int* __restrict__ bsum, int nb)
{
    const int lane = threadIdx.x;    // 64 threads
    int v0 = (lane      < nb) ? bsum[lane]      : 0;
    int v1 = (lane + 64 < nb) ? bsum[lane + 64] : 0;
    int t0 = v0;
    #pragma unroll
    for (int off = 1; off < 64; off <<= 1) {
        int u = __shfl_up(t0, off);
        if (lane >= off) t0 += u;
    }
    int total0 = __shfl(t0, 63);
    int t1 = v1;
    #pragma unroll
    for (int off = 1; off < 64; off <<= 1) {
        int u = __shfl_up(t1, off);
        if (lane >= off) t1 += u;
    }
    t1 += total0;
    if (lane      < nb) bsum[lane]      = t0 - v0;
    if (lane + 64 < nb) bsum[lane + 64] = t1 - v1;
}

// adds block offsets; writes final rowptr AND the fill-counter copy; rowptr[n]=E
__global__ __launch_bounds__(256) void k_scan3(
    int* __restrict__ rowptr, int* __restrict__ fill,
    const int* __restrict__ bsum, int n, int ecount)
{
    const int off = bsum[blockIdx.x];
    const int base = blockIdx.x * SCAN_CHUNK + threadIdx.x * 4;
    #pragma unroll
    for (int k = 0; k < 4; ++k) {
        int idx = base + k;
        if (idx < n) {
            int v = rowptr[idx] + off;
            rowptr[idx] = v;
            fill[idx]   = v;
        }
    }
    if (blockIdx.x == 0 && threadIdx.x == 0) rowptr[n] = ecount;
}

// ---------------- K4: fused edge-logit + counting-sort scatter --------------
__global__ __launch_bounds__(256) void k_scatter(
    const int* __restrict__ src, const int* __restrict__ tgt,
    const float* __restrict__ ew, const float* __restrict__ hs,
    const float* __restrict__ ht, int* __restrict__ fill,
    float2* __restrict__ edat, int ecount)
{
    int i = blockIdx.x * blockDim.x + threadIdx.x;
    if (i >= ecount) return;
    int s = src[i], t = tgt[i];
    float v = hs[s] + ht[t];
    v = (v > 0.f) ? v : 0.2f * v;          // leaky_relu slope 0.2
    v *= ew[i];
    int pos = atomicAdd(fill + t, 1);
    edat[pos] = make_float2(__int_as_float(s), v);
}

// guarded exp for online-softmax merges: maps NaN (from -inf - -inf) to ~0
__device__ __forceinline__ float expg(float d) {
    return __expf(fmaxf(d, -80.f));
}

// ---------------- K5: per-node softmax + aggregation (no atomics) -----------
// One wave per target node. Phase A: fused online max+sum over edges.
// Phase B: 4 groups x 16 lanes; group = edge, lane = 4 dims (bf16x4 gather).
__global__ __launch_bounds__(256) void k_node(
    const int* __restrict__ rowptr, const float2* __restrict__ edat,
    const unsigned short* __restrict__ hh, float* __restrict__ out, int n)
{
    const int lane = threadIdx.x & 63;
    const int wv   = threadIdx.x >> 6;
    const int t    = blockIdx.x * 4 + wv;
    if (t >= n) return;
    const int beg = rowptr[t], end = rowptr[t + 1];

    // Phase A: online softmax (max + sum-of-exp in one pass)
    float m = -INFINITY, s = 0.f;
    for (int j = beg + lane; j < end; j += 64) {
        float v = edat[j].y;
        float nm = fmaxf(m, v);
        s = s * expg(m - nm) + expg(v - nm);
        m = nm;
    }
    #pragma unroll
    for (int off = 32; off; off >>= 1) {
        float mo = __shfl_xor(m, off);
        float so = __shfl_xor(s, off);
        float nm = fmaxf(m, mo);
        s = s * expg(m - nm) + so * expg(mo - nm);
        m = nm;
    }
    const float rden = 1.f / (s + 1e-10f);

    // Phase B: out[t][:] = sum_j alpha_j * h[src_j][:], 4 edges in flight x2
    const int g  = lane >> 4;        // group 0..3 -> edge j+g
    const int l4 = lane & 15;        // 4 dims per lane
    float4 a0 = make_float4(0.f, 0.f, 0.f, 0.f);
    float4 a1 = make_float4(0.f, 0.f, 0.f, 0.f);
    int j = beg;
    for (; j + 8 <= end; j += 8) {
        float2 e0 = edat[j + g];
        float2 e1 = edat[j + 4 + g];
        int s0 = __float_as_int(e0.x);
        int s1 = __float_as_int(e1.x);
        ushort4 u0 = ((const ushort4*)(hh + (size_t)s0 * OUT_DIM))[l4];
        ushort4 u1 = ((const ushort4*)(hh + (size_t)s1 * OUT_DIM))[l4];
        float c0 = __expf(e0.y - m) * rden;
        float c1 = __expf(e1.y - m) * rden;
        a0.x += c0 * bf2f(u0.x); a0.y += c0 * bf2f(u0.y);
        a0.z += c0 * bf2f(u0.z); a0.w += c0 * bf2f(u0.w);
        a1.x += c1 * bf2f(u1.x); a1.y += c1 * bf2f(u1.y);
        a1.z += c1 * bf2f(u1.z); a1.w += c1 * bf2f(u1.w);
    }
    for (; j < end; j += 4) {
        int jj = j + g;
        bool valid = jj < end;
        float2 ed = edat[valid ? jj : (end - 1)];
        int sidx = __float_as_int(ed.x);
        ushort4 uv = ((const ushort4*)(hh + (size_t)sidx * OUT_DIM))[l4];
        float c = valid ? __expf(ed.y - m) * rden : 0.f;
        a0.x += c * bf2f(uv.x); a0.y += c * bf2f(uv.y);
        a0.z += c * bf2f(uv.z); a0.w += c * bf2f(uv.w);
    }
    a0.x += a1.x; a0.y += a1.y; a0.z += a1.z; a0.w += a1.w;

    #pragma unroll
    for (int off = 32; off >= 16; off >>= 1) {
        a0.x += __shfl_xor(a0.x, off);
        a0.y += __shfl_xor(a0.y, off);
        a0.z += __shfl_xor(a0.z, off);
        a0.w += __shfl_xor(a0.w, off);
    }
    if (g == 0)
        ((float4*)(out + (size_t)t * OUT_DIM))[l4] = a0;
}

extern "C" void kernel_launch(void* const* d_in, const int* in_sizes, int n_in,
                              void* d_out, int out_size, void* d_ws, size_t ws_size,
                              hipStream_t stream) {
    const float* x     = (const float*)d_in[0];
    const int*   eidx  = (const int*)d_in[1];
    const float* ew    = (const float*)d_in[2];
    const float* W     = (const float*)d_in[3];
    const float* a_src = (const float*)d_in[4];
    const float* a_tgt = (const float*)d_in[5];
    float* out = (float*)d_out;

    const int n = in_sizes[0] / IN_DIM;     // 100000
    const int E = in_sizes[2];              // 3200000
    const int* src = eidx;
    const int* tgt = eidx + E;
    const int NB = (n + SCAN_CHUNK - 1) / SCAN_CHUNK;   // 98 <= 128

    // Workspace layout (4-byte units, edat 8B-aligned). Total ~40 MB,
    // strictly inside R4's proven 52.8 MB footprint.
    float* ws = (float*)d_ws;
    unsigned short* hh = (unsigned short*)ws;  ws += (size_t)n * OUT_DIM / 2;
    float* hs     = ws;                 ws += n;
    float* ht     = ws;                 ws += n;
    int*   cnt    = (int*)ws;           ws += n;                  // hist, then fill
    int*   rowptr = (int*)ws;           ws += (n + 2);
    int*   bsum   = (int*)ws;           ws += 128;
    float2* edat  = (float2*)ws;        // E pairs (srcbits, e)

    hipMemsetAsync(cnt, 0, (size_t)n * sizeof(int), stream);

    k_linear<<<(n + LNODES - 1) / LNODES, 512, 0, stream>>>(x, W, a_src, a_tgt, hh, hs, ht, n);
    k_hist<<<(E + 255) / 256, 256, 0, stream>>>(tgt, cnt, E);
    k_scan1<<<NB, 256, 0, stream>>>(cnt, rowptr, bsum, n);
    k_scan2<<<1, 64, 0, stream>>>(bsum, NB);
    k_scan3<<<NB, 256, 0, stream>>>(rowptr, cnt, bsum, n, E);
    k_scatter<<<(E + 255) / 256, 256, 0, stream>>>(src, tgt, ew, hs, ht, cnt, edat, E);
    k_node<<<(n + 3) / 4, 256, 0, stream>>>(rowptr, edat, hh, out, n);
}